// Round 7
// baseline (1387.468 us; speedup 1.0000x reference)
//
#include <hip/hip_runtime.h>
#include <cstdint>
#include <cstddef>

typedef _Float16 half8 __attribute__((ext_vector_type(8)));
typedef _Float16 half4v __attribute__((ext_vector_type(4)));
typedef float f32x4 __attribute__((ext_vector_type(4)));

#define NCOL 512   // 2*M interleaved (re,im)
#define KY 256     // 2*N interleaved

__device__ __forceinline__ float shrinkf(float v, float eta) {
  float a = fabsf(v) - eta;           // LAMBD = 1.0
  return a > 0.0f ? copysignf(a, v) : 0.0f;
}

// ---------- table builders ----------
__global__ void build_wa(const float* __restrict__ A, _Float16* __restrict__ Wa) {
  int idx = blockIdx.x * 256 + threadIdx.x;     // 131072
  int n = idx >> 8, k = idx & 255;
  int p = n >> 1, c = n & 1, q = k >> 1, d = k & 1;
  const float* A0 = A;                // (256,128)
  const float* A1 = A + 256 * 128;
  float v;
  if (c == 0) v = (d == 0) ? A0[p * 128 + q] : -A1[p * 128 + q];
  else        v = (d == 0) ? A1[p * 128 + q] :  A0[p * 128 + q];
  Wa[idx] = (_Float16)v;
}

__global__ void build_wb(const float* __restrict__ B, _Float16* __restrict__ Wb) {
  int idx = blockIdx.x * 256 + threadIdx.x;     // 262144
  int n = idx >> 9, k = idx & 511;
  int p = n >> 1, c = n & 1, q = k >> 1, d = k & 1;
  const float* B0 = B;                // (256,256)
  const float* B1 = B + 256 * 256;
  float v;
  if (c == 0) v = (d == 0) ?  B0[p * 256 + q] : -B1[p * 256 + q];
  else        v = (d == 0) ?  B1[p * 256 + q] :  B0[p * 256 + q];
  Wb[idx] = (_Float16)v;
}

// ---------- fused LISTA chain ----------
// Block = 32 batch rows x 512 features, 512 threads / 8 waves; wave w owns
// features [w*64, w*64+64) x 32 batch. Per t:
//   u = realify(B)@x (MFMA, Wb from L2); x_next = shrink(x_old + g*(Ay-u))
// Sizing rationale (rounds 5/6 post-mortems):
//   acc 32 AGPR + ayv 16 VGPR + frags 32 -> ~105 regs total <= 128
//   => __launch_bounds__(512,4): 4 waves/SIMD, TWO blocks/CU resident.
//   Barriers drain only half the CU; 4 waves/SIMD hide L2 latency via TLP
//   (round 6 proved register-pipeline ILP spills at this budget).
// x DOUBLE-buffered in LDS (2 x 32KB): read (t-1)&1, write t&1
//   -> ONE barrier per iteration. 16B-chunk XOR swizzle as before.
__global__ __launch_bounds__(512, 4) void lista_fused(
    const float* __restrict__ y,
    const _Float16* __restrict__ Wa,
    const _Float16* __restrict__ Wb,
    float* __restrict__ out,
    const float* __restrict__ gammas,
    const float* __restrict__ etas) {
  __shared__ __align__(16) _Float16 xlds[2][32 * 512];   // 2 x 32 KB

  const int tid  = threadIdx.x;
  const int l16  = tid & 15;
  const int quad = (tid >> 4) & 3;
  const int wave = tid >> 6;          // 0..7 feature slice
  const int l7   = l16 & 7;
  const int b0   = blockIdx.x << 5;   // batch base (32 per block)
  const int fb   = wave << 6;         // feature base (64 per wave)
  const int fc   = wave << 3;         // feature base in 8-half chunks

  f32x4 acc[4][2];
#pragma unroll
  for (int i = 0; i < 4; ++i)
#pragma unroll
    for (int j = 0; j < 2; ++j) acc[i][j] = {0.f, 0.f, 0.f, 0.f};

  // ---- prologue: acc = Ay tile = Wa(feat,K) @ y^T(K,batch), K=256 ----
#pragma unroll 1
  for (int kt = 0; kt < 4; ++kt) {
#pragma unroll
    for (int ks = 0; ks < 2; ++ks) {
      const int k0 = kt * 64 + ks * 32 + quad * 8;
      half8 bf[2];
#pragma unroll
      for (int j = 0; j < 2; ++j) {
        const float* yp = y + (size_t)(b0 + j * 16 + l16) * KY + k0;
        f32x4 a = *(const f32x4*)yp;
        f32x4 b = *(const f32x4*)(yp + 4);
        half8 h;
        h[0] = (_Float16)a.x; h[1] = (_Float16)a.y;
        h[2] = (_Float16)a.z; h[3] = (_Float16)a.w;
        h[4] = (_Float16)b.x; h[5] = (_Float16)b.y;
        h[6] = (_Float16)b.z; h[7] = (_Float16)b.w;
        bf[j] = h;
      }
      half8 af[4];
#pragma unroll
      for (int i = 0; i < 4; ++i)
        af[i] = *(const half8*)(Wa + (size_t)(fb + i * 16 + l16) * KY + k0);
#pragma unroll
      for (int i = 0; i < 4; ++i)
#pragma unroll
        for (int j = 0; j < 2; ++j)
          acc[i][j] = __builtin_amdgcn_mfma_f32_16x16x32_f16(
              af[i], bf[j], acc[i][j], 0, 0, 0);
    }
  }

  // epilogue 0: Ay -> registers (fp16 packed); x0 = shrink(g0*Ay) -> LDS buf0
  const float g0 = gammas[0], e0 = etas[0];
  half4v ayv[4][2];
#pragma unroll
  for (int i = 0; i < 4; ++i) {
    const int cw = ((fc + i * 2 + (quad >> 1)) ^ l7) * 8 + (quad & 1) * 4;
#pragma unroll
    for (int j = 0; j < 2; ++j) {
      f32x4 v = acc[i][j];
      half4v a4 = {(_Float16)v.x, (_Float16)v.y, (_Float16)v.z, (_Float16)v.w};
      ayv[i][j] = a4;
      half4v x0 = {(_Float16)shrinkf(g0 * v.x, e0), (_Float16)shrinkf(g0 * v.y, e0),
                   (_Float16)shrinkf(g0 * v.z, e0), (_Float16)shrinkf(g0 * v.w, e0)};
      *(half4v*)(xlds[0] + (j * 16 + l16) * NCOL + cw) = x0;
    }
  }

  // ---- main loop: x = shrink(x + g*(Ay - Wb@x)), t = 1..10 ----
#pragma unroll 1
  for (int t = 1; t <= 10; ++t) {
    __syncthreads();                  // prior epilogue's x writes visible
    const _Float16* xr = xlds[(t - 1) & 1];
    _Float16* xw = xlds[t & 1];

#pragma unroll
    for (int i = 0; i < 4; ++i)
#pragma unroll
      for (int j = 0; j < 2; ++j) acc[i][j] = {0.f, 0.f, 0.f, 0.f};

#pragma unroll 2
    for (int kt = 0; kt < 8; ++kt) {
#pragma unroll
      for (int ks = 0; ks < 2; ++ks) {
        half8 bf[2];
#pragma unroll
        for (int j = 0; j < 2; ++j)
          bf[j] = *(const half8*)(xr + (j * 16 + l16) * NCOL + kt * 64 +
                                  ((ks * 4 + quad) ^ l7) * 8);
        const size_t wk = (size_t)(kt * 64 + ks * 32 + quad * 8);
        half8 af[4];
#pragma unroll
        for (int i = 0; i < 4; ++i)
          af[i] = *(const half8*)(Wb + (size_t)(fb + i * 16 + l16) * NCOL + wk);
#pragma unroll
        for (int i = 0; i < 4; ++i)
#pragma unroll
          for (int j = 0; j < 2; ++j)
            acc[i][j] = __builtin_amdgcn_mfma_f32_16x16x32_f16(
                af[i], bf[j], acc[i][j], 0, 0, 0);
      }
    }

    const float g = gammas[t], eta = etas[t];
    // no second barrier: x_old reads hit the read buffer (stable this t);
    // writes go to the write buffer, published by next iteration's barrier.

    if (t < 10) {
#pragma unroll
      for (int i = 0; i < 4; ++i) {
        const int cw = ((fc + i * 2 + (quad >> 1)) ^ l7) * 8 + (quad & 1) * 4;
#pragma unroll
        for (int j = 0; j < 2; ++j) {
          half4v a4 = ayv[i][j];
          half4v xo = *(const half4v*)(xr + (j * 16 + l16) * NCOL + cw);
          f32x4 u = acc[i][j];
          half4v xn;
#pragma unroll
          for (int r = 0; r < 4; ++r) {
            float val = fmaf(g, (float)a4[r] - u[r], (float)xo[r]);
            xn[r] = (_Float16)shrinkf(val, eta);
          }
          *(half4v*)(xw + (j * 16 + l16) * NCOL + cw) = xn;
        }
      }
    } else {
#pragma unroll
      for (int i = 0; i < 4; ++i) {
        const int cw = ((fc + i * 2 + (quad >> 1)) ^ l7) * 8 + (quad & 1) * 4;
#pragma unroll
        for (int j = 0; j < 2; ++j) {
          half4v a4 = ayv[i][j];
          half4v xo = *(const half4v*)(xr + (j * 16 + l16) * NCOL + cw);
          f32x4 u = acc[i][j];
          f32x4 o;
#pragma unroll
          for (int r = 0; r < 4; ++r) {
            float val = fmaf(g, (float)a4[r] - u[r], (float)xo[r]);
            o[r] = shrinkf(val, eta);
          }
          *(f32x4*)(out + (size_t)(b0 + j * 16 + l16) * NCOL + fb + i * 16 + quad * 4) = o;
        }
      }
    }
  }
}

extern "C" void kernel_launch(void* const* d_in, const int* in_sizes, int n_in,
                              void* d_out, int out_size, void* d_ws, size_t ws_size,
                              hipStream_t stream) {
  const float* y      = (const float*)d_in[0];
  const float* A      = (const float*)d_in[1];
  const float* B      = (const float*)d_in[2];
  const float* etas   = (const float*)d_in[3];
  const float* gammas = (const float*)d_in[4];

  char* ws = (char*)d_ws;
  _Float16* Wa = (_Float16*)ws;                       // 512*256*2 = 256 KB
  _Float16* Wb = (_Float16*)(ws + 262144);            // 512*512*2 = 512 KB

  hipLaunchKernelGGL(build_wa, dim3(512), dim3(256), 0, stream, A, Wa);
  hipLaunchKernelGGL(build_wb, dim3(1024), dim3(256), 0, stream, B, Wb);
  hipLaunchKernelGGL(lista_fused, dim3(2048), dim3(512), 0, stream,
                     y, Wa, Wb, (float*)d_out, gammas, etas);
}

// Round 8
// 566.215 us; speedup vs baseline: 2.4504x; 2.4504x over previous
//
#include <hip/hip_runtime.h>
#include <cstdint>
#include <cstddef>

typedef _Float16 half8 __attribute__((ext_vector_type(8)));
typedef _Float16 half4v __attribute__((ext_vector_type(4)));
typedef float f32x4 __attribute__((ext_vector_type(4)));

#define NCOL 512   // 2*M interleaved (re,im)
#define KY 256     // 2*N interleaved

__device__ __forceinline__ float shrinkf(float v, float eta) {
  float a = fabsf(v) - eta;           // LAMBD = 1.0
  return a > 0.0f ? copysignf(a, v) : 0.0f;
}

// ---------- table builders (MFMA-FRAGMENT order) ----------
// Fragment addressing: frag f holds 64 lanes x 8 halves (1KB contiguous).
// For A-operand frag (w, s, i): lane (l16,quad), elem e maps to
//   row = w*64 + i*16 + l16,  k = s*32 + quad*8 + e.
// WaF: w=0..7, s=0..7  (K=256):  idx = (((w*8+s)*4+i)*64+lane)*8+e
__global__ void build_wa(const float* __restrict__ A, _Float16* __restrict__ Wa) {
  int idx = blockIdx.x * 256 + threadIdx.x;     // 131072
  int e = idx & 7, lane = (idx >> 3) & 63, i = (idx >> 9) & 3;
  int s = (idx >> 11) & 7, w = idx >> 14;
  int l16 = lane & 15, quad = lane >> 4;
  int n = w * 64 + i * 16 + l16;
  int k = s * 32 + quad * 8 + e;
  int p = n >> 1, c = n & 1, q = k >> 1, d = k & 1;
  const float* A0 = A;                // (256,128)
  const float* A1 = A + 256 * 128;
  float v;
  if (c == 0) v = (d == 0) ? A0[p * 128 + q] : -A1[p * 128 + q];
  else        v = (d == 0) ? A1[p * 128 + q] :  A0[p * 128 + q];
  Wa[idx] = (_Float16)v;
}

// WbF: w=0..7, s=0..15 (K=512):  idx = (((w*16+s)*4+i)*64+lane)*8+e
__global__ void build_wb(const float* __restrict__ B, _Float16* __restrict__ Wb) {
  int idx = blockIdx.x * 256 + threadIdx.x;     // 262144
  int e = idx & 7, lane = (idx >> 3) & 63, i = (idx >> 9) & 3;
  int s = (idx >> 11) & 15, w = idx >> 15;
  int l16 = lane & 15, quad = lane >> 4;
  int n = w * 64 + i * 16 + l16;
  int k = s * 32 + quad * 8 + e;
  int p = n >> 1, c = n & 1, q = k >> 1, d = k & 1;
  const float* B0 = B;                // (256,256)
  const float* B1 = B + 256 * 256;
  float v;
  if (c == 0) v = (d == 0) ?  B0[p * 256 + q] : -B1[p * 256 + q];
  else        v = (d == 0) ?  B1[p * 256 + q] :  B0[p * 256 + q];
  Wb[idx] = (_Float16)v;
}

// ---------- fused LISTA chain ----------
// Round-5 structure (best fused: 64 batch x 512 feat, 8 waves, wave owns
// 64 feat x 64 batch, Ay in regs, 2 barriers/iter) with all layouts in
// MFMA-fragment order:
//  - WaF/WbF global tables: af loads = 1KB contiguous per wave (4 lines,
//    was 16 scattered lines -> 4x fewer L2 requests).
//  - x in LDS in B-frag order: bf ds_read_b128 fully sequential -> ZERO
//    bank conflicts (was ~8-way, 31.5M conflict cycles).
__global__ __launch_bounds__(512, 2) void lista_fused(
    const float* __restrict__ y,
    const _Float16* __restrict__ Wa,
    const _Float16* __restrict__ Wb,
    float* __restrict__ out,
    const float* __restrict__ gammas,
    const float* __restrict__ etas) {
  __shared__ __align__(16) _Float16 xf[64 * 512];   // 64 KB, B-frag order

  const int tid  = threadIdx.x;
  const int lane = tid & 63;
  const int l16  = tid & 15;
  const int quad = (tid >> 4) & 3;
  const int wave = tid >> 6;          // 0..7 feature slice
  const int b0   = blockIdx.x << 6;   // batch base (64 per block)
  const int fb   = wave << 6;         // feature base (64 per wave)

  f32x4 acc[4][4];
#pragma unroll
  for (int i = 0; i < 4; ++i)
#pragma unroll
    for (int j = 0; j < 4; ++j) acc[i][j] = {0.f, 0.f, 0.f, 0.f};

  // ---- prologue: acc = Ay tile = Wa(feat,K) @ y^T(K,batch), K=256 ----
#pragma unroll 1
  for (int s = 0; s < 8; ++s) {
    const int k0 = s * 32 + quad * 8;
    half8 bf[4];
#pragma unroll
    for (int j = 0; j < 4; ++j) {
      const float* yp = y + (size_t)(b0 + j * 16 + l16) * KY + k0;
      f32x4 a = *(const f32x4*)yp;
      f32x4 b = *(const f32x4*)(yp + 4);
      half8 h;
      h[0] = (_Float16)a.x; h[1] = (_Float16)a.y;
      h[2] = (_Float16)a.z; h[3] = (_Float16)a.w;
      h[4] = (_Float16)b.x; h[5] = (_Float16)b.y;
      h[6] = (_Float16)b.z; h[7] = (_Float16)b.w;
      bf[j] = h;
    }
    half8 af[4];
#pragma unroll
    for (int i = 0; i < 4; ++i)
      af[i] = *(const half8*)(Wa + (size_t)(((wave * 8 + s) * 4 + i) * 64 + lane) * 8);
#pragma unroll
    for (int i = 0; i < 4; ++i)
#pragma unroll
      for (int j = 0; j < 4; ++j)
        acc[i][j] = __builtin_amdgcn_mfma_f32_16x16x32_f16(
            af[i], bf[j], acc[i][j], 0, 0, 0);
  }

  // epilogue 0: Ay -> registers (fp16 packed); x0 = shrink(g0*Ay) -> LDS frag
  // D element (feature kk+r, batch j*16+l16) -> frag (s=kk>>5, j),
  //   lane' = ((kk>>3)&3)*16 + l16, elem (quad&1)*4 + r.
  const float g0 = gammas[0], e0 = etas[0];
  half4v ayv[4][4];
#pragma unroll
  for (int i = 0; i < 4; ++i) {
    const int kk = fb + i * 16 + quad * 4;
    const size_t xoff = (size_t)((kk >> 5) * 4) * 512 +
                        (size_t)((((kk >> 3) & 3) * 16 + l16) * 8) + (quad & 1) * 4;
#pragma unroll
    for (int j = 0; j < 4; ++j) {
      f32x4 v = acc[i][j];
      half4v a4 = {(_Float16)v.x, (_Float16)v.y, (_Float16)v.z, (_Float16)v.w};
      ayv[i][j] = a4;
      half4v x0 = {(_Float16)shrinkf(g0 * v.x, e0), (_Float16)shrinkf(g0 * v.y, e0),
                   (_Float16)shrinkf(g0 * v.z, e0), (_Float16)shrinkf(g0 * v.w, e0)};
      *(half4v*)(xf + xoff + (size_t)j * 512) = x0;
    }
  }

  // ---- main loop: x = shrink(x + g*(Ay - Wb@x)), t = 1..10 ----
#pragma unroll 1
  for (int t = 1; t <= 10; ++t) {
    __syncthreads();                  // x writes visible to all waves

#pragma unroll
    for (int i = 0; i < 4; ++i)
#pragma unroll
      for (int j = 0; j < 4; ++j) acc[i][j] = {0.f, 0.f, 0.f, 0.f};

#pragma unroll 2
    for (int s = 0; s < 16; ++s) {
      half8 bf[4];
#pragma unroll
      for (int j = 0; j < 4; ++j)
        bf[j] = *(const half8*)(xf + (size_t)((s * 4 + j) * 64 + lane) * 8);
      half8 af[4];
#pragma unroll
      for (int i = 0; i < 4; ++i)
        af[i] = *(const half8*)(Wb + (size_t)(((wave * 16 + s) * 4 + i) * 64 + lane) * 8);
#pragma unroll
      for (int i = 0; i < 4; ++i)
#pragma unroll
        for (int j = 0; j < 4; ++j)
          acc[i][j] = __builtin_amdgcn_mfma_f32_16x16x32_f16(
              af[i], bf[j], acc[i][j], 0, 0, 0);
    }

    const float g = gammas[t], eta = etas[t];
    __syncthreads();                  // all reads of x done before overwrite

    if (t < 10) {
#pragma unroll
      for (int i = 0; i < 4; ++i) {
        const int kk = fb + i * 16 + quad * 4;
        const size_t xoff = (size_t)((kk >> 5) * 4) * 512 +
                            (size_t)((((kk >> 3) & 3) * 16 + l16) * 8) + (quad & 1) * 4;
#pragma unroll
        for (int j = 0; j < 4; ++j) {
          half4v a4 = ayv[i][j];
          half4v xo = *(const half4v*)(xf + xoff + (size_t)j * 512);
          f32x4 u = acc[i][j];
          half4v xn;
#pragma unroll
          for (int r = 0; r < 4; ++r) {
            float val = fmaf(g, (float)a4[r] - u[r], (float)xo[r]);
            xn[r] = (_Float16)shrinkf(val, eta);
          }
          *(half4v*)(xf + xoff + (size_t)j * 512) = xn;
        }
      }
    } else {
#pragma unroll
      for (int i = 0; i < 4; ++i) {
        const int kk = fb + i * 16 + quad * 4;
        const size_t xoff = (size_t)((kk >> 5) * 4) * 512 +
                            (size_t)((((kk >> 3) & 3) * 16 + l16) * 8) + (quad & 1) * 4;
#pragma unroll
        for (int j = 0; j < 4; ++j) {
          half4v a4 = ayv[i][j];
          half4v xo = *(const half4v*)(xf + xoff + (size_t)j * 512);
          f32x4 u = acc[i][j];
          f32x4 o;
#pragma unroll
          for (int r = 0; r < 4; ++r) {
            float val = fmaf(g, (float)a4[r] - u[r], (float)xo[r]);
            o[r] = shrinkf(val, eta);
          }
          *(f32x4*)(out + (size_t)(b0 + j * 16 + l16) * NCOL + fb + i * 16 + quad * 4) = o;
        }
      }
    }
  }
}

extern "C" void kernel_launch(void* const* d_in, const int* in_sizes, int n_in,
                              void* d_out, int out_size, void* d_ws, size_t ws_size,
                              hipStream_t stream) {
  const float* y      = (const float*)d_in[0];
  const float* A      = (const float*)d_in[1];
  const float* B      = (const float*)d_in[2];
  const float* etas   = (const float*)d_in[3];
  const float* gammas = (const float*)d_in[4];

  char* ws = (char*)d_ws;
  _Float16* Wa = (_Float16*)ws;                       // 512*256*2 = 256 KB
  _Float16* Wb = (_Float16*)(ws + 262144);            // 512*512*2 = 512 KB

  hipLaunchKernelGGL(build_wa, dim3(512), dim3(256), 0, stream, A, Wa);
  hipLaunchKernelGGL(build_wb, dim3(1024), dim3(256), 0, stream, B, Wb);
  hipLaunchKernelGGL(lista_fused, dim3(1024), dim3(512), 0, stream,
                     y, Wa, Wb, (float*)d_out, gammas, etas);
}